// Round 1
// baseline (9173.338 us; speedup 1.0000x reference)
//
#include <hip/hip_runtime.h>

#define H 128

// ---------------- helpers ----------------

__device__ __forceinline__ unsigned fkey(float f) {
    unsigned u = __float_as_uint(f);
    return (u & 0x80000000u) ? ~u : (u | 0x80000000u);
}
__device__ __forceinline__ float funkey(unsigned k) {
    unsigned u = (k & 0x80000000u) ? (k & 0x7FFFFFFFu) : ~k;
    return __uint_as_float(u);
}

__global__ void fill_u32(unsigned* __restrict__ p, unsigned v, int n) {
    int i = blockIdx.x * blockDim.x + threadIdx.x;
    if (i < n) p[i] = v;
}

// ---------------- fuse: sat/nei linear + gate ----------------
// one block (128 threads) per node
__global__ void fuse_kernel(const float* __restrict__ x,
                            const float* __restrict__ sat_w, const float* __restrict__ sat_b,
                            const float* __restrict__ neigh_w, const float* __restrict__ neigh_b,
                            const float* __restrict__ fus_w, const float* __restrict__ fus_b,
                            float* __restrict__ h0, int N) {
    int n = blockIdx.x;
    int f = threadIdx.x; // 0..127
    __shared__ float xs[64];
    __shared__ float red[128];
    if (f < 64) xs[f] = x[(size_t)n * 64 + f];
    __syncthreads();
    float s_acc = sat_b[f], n_acc = neigh_b[f];
#pragma unroll 8
    for (int k = 0; k < 32; ++k) {
        s_acc += xs[k] * sat_w[f * 32 + k];
        n_acc += xs[32 + k] * neigh_w[f * 32 + k];
    }
    float sat = fmaxf(s_acc, 0.f), nei = fmaxf(n_acc, 0.f);
    red[f] = sat * fus_w[f] + nei * fus_w[128 + f];
    __syncthreads();
    for (int off = 64; off > 0; off >>= 1) {
        if (f < off) red[f] += red[f + off];
        __syncthreads();
    }
    float gate = 1.f / (1.f + expf(-(red[0] + fus_b[0])));
    h0[(size_t)n * H + f] = gate * sat + (1.f - gate) * nei;
}

// ---------------- 128x128 GEMM: out[n][col] = dot(in[n], w[col]) ----------------
// 256 threads, 8 nodes per block, each thread does 4 (node,col) dots
#define NPB 8
__global__ void gemm128(const float* __restrict__ in, const float* __restrict__ w,
                        const float* __restrict__ bias, int do_relu,
                        float* __restrict__ out, int N) {
    __shared__ float xs[NPB][H];
    int block0 = blockIdx.x * NPB;
    int t = threadIdx.x;
    for (int i = t; i < NPB * H; i += 256) {
        int nn = i >> 7, f = i & 127;
        int n = block0 + nn;
        xs[nn][f] = (n < N) ? in[(size_t)n * H + f] : 0.f;
    }
    __syncthreads();
    int col = t & 127;
    int half = t >> 7;
    float acc[4] = {0.f, 0.f, 0.f, 0.f};
    const float4* w4 = (const float4*)(w + (size_t)col * H);
    for (int k4 = 0; k4 < H / 4; ++k4) {
        float4 wv = w4[k4];
#pragma unroll
        for (int j = 0; j < 4; ++j) {
            float4 xv = ((const float4*)xs[half * 4 + j])[k4];
            acc[j] += wv.x * xv.x + wv.y * xv.y + wv.z * xv.z + wv.w * xv.w;
        }
    }
    float bv = bias ? bias[col] : 0.f;
#pragma unroll
    for (int j = 0; j < 4; ++j) {
        int n = block0 + half * 4 + j;
        if (n < N) {
            float v = acc[j] + bv;
            if (do_relu) v = fmaxf(v, 0.f);
            out[(size_t)n * H + col] = v;
        }
    }
}

// ---------------- attention logits per node ----------------
// one wave per node
__global__ void attn_logits(const float* __restrict__ h1,
                            const float* __restrict__ a_s, const float* __restrict__ a_d,
                            float* __restrict__ al_s, float* __restrict__ al_d, int N) {
    int wid = (blockIdx.x * blockDim.x + threadIdx.x) >> 6;
    int lane = threadIdx.x & 63;
    if (wid >= N) return;
    const float* hr = h1 + (size_t)wid * H;
    float h_lo = hr[lane], h_hi = hr[lane + 64];
    float ps = h_lo * a_s[lane] + h_hi * a_s[lane + 64];
    float pd = h_lo * a_d[lane] + h_hi * a_d[lane + 64];
    for (int off = 32; off > 0; off >>= 1) {
        ps += __shfl_down(ps, off);
        pd += __shfl_down(pd, off);
    }
    if (lane == 0) { al_s[wid] = ps; al_d[wid] = pd; }
}

// ---------------- edge pass 1: leaky-relu logit + segment max ----------------
__global__ void edge_alpha(const int* __restrict__ src, const int* __restrict__ dst,
                           const float* __restrict__ al_s, const float* __restrict__ al_d,
                           unsigned* __restrict__ mkey, int E, int Etot) {
    int e = blockIdx.x * blockDim.x + threadIdx.x;
    if (e >= Etot) return;
    int s = (e < E) ? src[e] : (e - E);
    int d = (e < E) ? dst[e] : (e - E);
    float a = al_s[s] + al_d[d];
    a = (a > 0.f) ? a : 0.2f * a;
    atomicMax(mkey + d, fkey(a));
}

// ---------------- edge pass 2: exp, denom sum, unnormalized aggregate ----------------
// one wave per edge; lanes split the 128 features (2 each)
__global__ void edge_expagg(const int* __restrict__ src, const int* __restrict__ dst,
                            const float* __restrict__ al_s, const float* __restrict__ al_d,
                            const unsigned* __restrict__ mkey, const float* __restrict__ h1,
                            float* __restrict__ ssum, float* __restrict__ agg,
                            int E, int Etot) {
    int gw = (blockIdx.x * blockDim.x + threadIdx.x) >> 6;
    int lane = threadIdx.x & 63;
    if (gw >= Etot) return;
    int s = (gw < E) ? src[gw] : (gw - E);
    int d = (gw < E) ? dst[gw] : (gw - E);
    float a = al_s[s] + al_d[d];
    a = (a > 0.f) ? a : 0.2f * a;
    float ev = __expf(a - funkey(mkey[d]));
    if (lane == 0) atomicAdd(ssum + d, ev);
    const float2 hv = *(const float2*)(h1 + (size_t)s * H + lane * 2);
    float* ap = agg + (size_t)d * H + lane * 2;
    atomicAdd(ap, ev * hv.x);
    atomicAdd(ap + 1, ev * hv.y);
}

// ---------------- BN stats: per-feature sum & sumsq of y = agg/(s+eps) ----------------
__global__ void bn_stats(const float* __restrict__ agg, const float* __restrict__ ssum,
                         float* __restrict__ accum, int N) {
    int f = threadIdx.x & 127;
    int half = threadIdx.x >> 7;
    float sum = 0.f, sumsq = 0.f;
    for (int n = blockIdx.x * 2 + half; n < N; n += gridDim.x * 2) {
        float inv = 1.f / (ssum[n] + 1e-16f);
        float y = agg[(size_t)n * H + f] * inv;
        sum += y;
        sumsq += y * y;
    }
    __shared__ float ls[2][128], ls2[2][128];
    ls[half][f] = sum;
    ls2[half][f] = sumsq;
    __syncthreads();
    if (half == 0) {
        atomicAdd(accum + f, ls[0][f] + ls[1][f]);
        atomicAdd(accum + 128 + f, ls2[0][f] + ls2[1][f]);
    }
}

// ---------------- BN apply + relu + residual (in-place on agg) ----------------
__global__ void bn_apply(float* __restrict__ agg, const float* __restrict__ ssum,
                         const float* __restrict__ accum,
                         const float* __restrict__ g, const float* __restrict__ be,
                         const float* __restrict__ res, int N) {
    int i = blockIdx.x * blockDim.x + threadIdx.x;
    if (i >= N * H) return;
    int f = i & 127, n = i >> 7;
    float Ninv = 1.f / (float)N;
    float mu = accum[f] * Ninv;
    float var = accum[128 + f] * Ninv - mu * mu;
    float y = agg[i] / (ssum[n] + 1e-16f);
    float v = (y - mu) * rsqrtf(var + 1e-5f) * g[f] + be[f];
    agg[i] = fmaxf(v, 0.f) + res[i];
}

// ---------------- final fc2: [N,128] -> [N,16] ----------------
__global__ void fc2_kernel(const float* __restrict__ in, const float* __restrict__ w,
                           const float* __restrict__ b, float* __restrict__ out,
                           int N, int OUT) {
    __shared__ float wsm[16 * 132];
    for (int i = threadIdx.x; i < OUT * H; i += 256) {
        int o = i >> 7, k = i & 127;
        wsm[o * 132 + k] = w[i];
    }
    __syncthreads();
    int o = threadIdx.x & 15;
    int nn = threadIdx.x >> 4;
    int n = blockIdx.x * 16 + nn;
    if (n >= N || o >= OUT) return;
    const float* xr = in + (size_t)n * H;
    const float* wr = wsm + o * 132;
    float acc = b[o];
#pragma unroll 8
    for (int k = 0; k < H; k += 4) {
        acc += xr[k] * wr[k] + xr[k + 1] * wr[k + 1] + xr[k + 2] * wr[k + 2] + xr[k + 3] * wr[k + 3];
    }
    out[(size_t)n * OUT + o] = acc;
}

// ---------------- launch ----------------

extern "C" void kernel_launch(void* const* d_in, const int* in_sizes, int n_in,
                              void* d_out, int out_size, void* d_ws, size_t ws_size,
                              hipStream_t stream) {
    const float* x       = (const float*)d_in[0];
    const int*   ei      = (const int*)d_in[1];
    const float* sat_w   = (const float*)d_in[2];
    const float* sat_b   = (const float*)d_in[3];
    const float* neigh_w = (const float*)d_in[4];
    const float* neigh_b = (const float*)d_in[5];
    const float* fus_w   = (const float*)d_in[6];
    const float* fus_b   = (const float*)d_in[7];
    const float* w1      = (const float*)d_in[8];
    const float* as1     = (const float*)d_in[9];
    const float* ad1     = (const float*)d_in[10];
    const float* g1      = (const float*)d_in[12];
    const float* be1     = (const float*)d_in[13];
    const float* w2      = (const float*)d_in[14];
    const float* as2     = (const float*)d_in[15];
    const float* ad2     = (const float*)d_in[16];
    const float* g2      = (const float*)d_in[18];
    const float* be2     = (const float*)d_in[19];
    const float* fc1_w   = (const float*)d_in[20];
    const float* fc1_b   = (const float*)d_in[21];
    const float* fc2_w   = (const float*)d_in[22];
    const float* fc2_b   = (const float*)d_in[23];

    int N = in_sizes[0] / 64;
    int E = in_sizes[1] / 2;
    int Etot = E + N;
    int OUT = in_sizes[23];

    float* ws   = (float*)d_ws;
    float* h0   = ws;                       // N*H  (fuse out / layer2 agg+out)
    float* hA   = h0 + (size_t)N * H;       // N*H  (gemm out / fc1 out)
    float* agg  = hA + (size_t)N * H;       // N*H  (layer1 agg+out / layer2 residual)
    float* al_s = agg + (size_t)N * H;      // N
    float* al_d = al_s + N;                 // N
    float* ssum = al_d + N;                 // N
    unsigned* mkey = (unsigned*)(ssum + N); // N
    float* accum = (float*)(mkey + N);      // 256

    const int* srcp = ei;
    const int* dstp = ei + E;

    dim3 b256(256);
    int gEdge = (Etot + 255) / 256;
    int gEdgeWave = (Etot * 64 + 255) / 256;
    int gGemm = (N + NPB - 1) / NPB;
    int gNH = (N * H + 255) / 256;

    // ---- fuse ----
    fuse_kernel<<<N, 128, 0, stream>>>(x, sat_w, sat_b, neigh_w, neigh_b, fus_w, fus_b, h0, N);

    // ================= GAT layer 1 (in: h0, agg buf: agg, out: agg) =================
    gemm128<<<gGemm, b256, 0, stream>>>(h0, w1, nullptr, 0, hA, N);
    attn_logits<<<(N + 3) / 4, b256, 0, stream>>>(hA, as1, ad1, al_s, al_d, N);
    // zero: agg (N*H) and ssum+mkey+accum (2N+256)
    fill_u32<<<gNH, b256, 0, stream>>>((unsigned*)agg, 0u, N * H);
    fill_u32<<<(2 * N + 256 + 255) / 256, b256, 0, stream>>>((unsigned*)ssum, 0u, 2 * N + 256);
    edge_alpha<<<gEdge, b256, 0, stream>>>(srcp, dstp, al_s, al_d, mkey, E, Etot);
    edge_expagg<<<gEdgeWave, b256, 0, stream>>>(srcp, dstp, al_s, al_d, mkey, hA, ssum, agg, E, Etot);
    bn_stats<<<512, b256, 0, stream>>>(agg, ssum, accum, N);
    bn_apply<<<gNH, b256, 0, stream>>>(agg, ssum, accum, g1, be1, h0, N);

    // ================= GAT layer 2 (in: agg, agg buf: h0, out: h0) =================
    gemm128<<<gGemm, b256, 0, stream>>>(agg, w2, nullptr, 0, hA, N);
    attn_logits<<<(N + 3) / 4, b256, 0, stream>>>(hA, as2, ad2, al_s, al_d, N);
    fill_u32<<<gNH, b256, 0, stream>>>((unsigned*)h0, 0u, N * H);
    fill_u32<<<(2 * N + 256 + 255) / 256, b256, 0, stream>>>((unsigned*)ssum, 0u, 2 * N + 256);
    edge_alpha<<<gEdge, b256, 0, stream>>>(srcp, dstp, al_s, al_d, mkey, E, Etot);
    edge_expagg<<<gEdgeWave, b256, 0, stream>>>(srcp, dstp, al_s, al_d, mkey, hA, ssum, h0, E, Etot);
    bn_stats<<<512, b256, 0, stream>>>(h0, ssum, accum, N);
    bn_apply<<<gNH, b256, 0, stream>>>(h0, ssum, accum, g2, be2, agg, N);

    // ================= head =================
    gemm128<<<gGemm, b256, 0, stream>>>(h0, fc1_w, fc1_b, 1, hA, N);
    fc2_kernel<<<(N + 15) / 16, b256, 0, stream>>>(hA, fc2_w, fc2_b, (float*)d_out, N, OUT);
}

// Round 2
// 7194.968 us; speedup vs baseline: 1.2750x; 1.2750x over previous
//
#include <hip/hip_runtime.h>

#define H 128

__global__ void fill_u32(unsigned* __restrict__ p, unsigned v, int n) {
    int i = blockIdx.x * blockDim.x + threadIdx.x;
    if (i < n) p[i] = v;
}

// ---------------- fuse: sat/nei linear + gate ----------------
// one block (128 threads) per node
__global__ void fuse_kernel(const float* __restrict__ x,
                            const float* __restrict__ sat_w, const float* __restrict__ sat_b,
                            const float* __restrict__ neigh_w, const float* __restrict__ neigh_b,
                            const float* __restrict__ fus_w, const float* __restrict__ fus_b,
                            float* __restrict__ h0, int N) {
    int n = blockIdx.x;
    int f = threadIdx.x; // 0..127
    __shared__ float xs[64];
    __shared__ float red[128];
    if (f < 64) xs[f] = x[(size_t)n * 64 + f];
    __syncthreads();
    float s_acc = sat_b[f], n_acc = neigh_b[f];
#pragma unroll 8
    for (int k = 0; k < 32; ++k) {
        s_acc += xs[k] * sat_w[f * 32 + k];
        n_acc += xs[32 + k] * neigh_w[f * 32 + k];
    }
    float sat = fmaxf(s_acc, 0.f), nei = fmaxf(n_acc, 0.f);
    red[f] = sat * fus_w[f] + nei * fus_w[128 + f];
    __syncthreads();
    for (int off = 64; off > 0; off >>= 1) {
        if (f < off) red[f] += red[f + off];
        __syncthreads();
    }
    float gate = 1.f / (1.f + expf(-(red[0] + fus_b[0])));
    h0[(size_t)n * H + f] = gate * sat + (1.f - gate) * nei;
}

// ---------------- 128x128 GEMM ----------------
#define NPB 8
__global__ void gemm128(const float* __restrict__ in, const float* __restrict__ w,
                        const float* __restrict__ bias, int do_relu,
                        float* __restrict__ out, int N) {
    __shared__ float xs[NPB][H];
    int block0 = blockIdx.x * NPB;
    int t = threadIdx.x;
    for (int i = t; i < NPB * H; i += 256) {
        int nn = i >> 7, f = i & 127;
        int n = block0 + nn;
        xs[nn][f] = (n < N) ? in[(size_t)n * H + f] : 0.f;
    }
    __syncthreads();
    int col = t & 127;
    int half = t >> 7;
    float acc[4] = {0.f, 0.f, 0.f, 0.f};
    const float4* w4 = (const float4*)(w + (size_t)col * H);
    for (int k4 = 0; k4 < H / 4; ++k4) {
        float4 wv = w4[k4];
#pragma unroll
        for (int j = 0; j < 4; ++j) {
            float4 xv = ((const float4*)xs[half * 4 + j])[k4];
            acc[j] += wv.x * xv.x + wv.y * xv.y + wv.z * xv.z + wv.w * xv.w;
        }
    }
    float bv = bias ? bias[col] : 0.f;
#pragma unroll
    for (int j = 0; j < 4; ++j) {
        int n = block0 + half * 4 + j;
        if (n < N) {
            float v = acc[j] + bv;
            if (do_relu) v = fmaxf(v, 0.f);
            out[(size_t)n * H + col] = v;
        }
    }
}

// ---------------- attention logits per node (one wave per node) ----------------
__global__ void attn_logits(const float* __restrict__ h1,
                            const float* __restrict__ a_s, const float* __restrict__ a_d,
                            float* __restrict__ al_s, float* __restrict__ al_d, int N) {
    int wid = (blockIdx.x * blockDim.x + threadIdx.x) >> 6;
    int lane = threadIdx.x & 63;
    if (wid >= N) return;
    const float* hr = h1 + (size_t)wid * H;
    float h_lo = hr[lane], h_hi = hr[lane + 64];
    float ps = h_lo * a_s[lane] + h_hi * a_s[lane + 64];
    float pd = h_lo * a_d[lane] + h_hi * a_d[lane + 64];
    for (int off = 32; off > 0; off >>= 1) {
        ps += __shfl_down(ps, off);
        pd += __shfl_down(pd, off);
    }
    if (lane == 0) { al_s[wid] = ps; al_d[wid] = pd; }
}

// ---------------- CSR build: 8-copy histogram (localized atomics) ----------------
__global__ void hist_kernel(const int* __restrict__ dst, int* __restrict__ cnt8,
                            int E, int Etot, int N) {
    int e = blockIdx.x * blockDim.x + threadIdx.x;
    if (e >= Etot) return;
    int c = blockIdx.x & 7;
    int d = (e < E) ? dst[e] : (e - E);
    atomicAdd(cnt8 + (size_t)c * N + d, 1);
}

// single-block scan: rowptr (exclusive over node totals) + per-copy cursors (in-place over cnt8)
__global__ void scan_kernel(int* cnt8, int* __restrict__ rowptr, int N) {
    __shared__ int tmp[1024];
    int tid = threadIdx.x;
    int CH = (N + 1023) / 1024;
    int start = tid * CH;
    int end = min(start + CH, N);
    int s = 0;
    for (int i = start; i < end; ++i) {
        int t = 0;
#pragma unroll
        for (int c = 0; c < 8; ++c) t += cnt8[(size_t)c * N + i];
        s += t;
    }
    tmp[tid] = s;
    __syncthreads();
    for (int off = 1; off < 1024; off <<= 1) {
        int t = (tid >= off) ? tmp[tid - off] : 0;
        __syncthreads();
        tmp[tid] += t;
        __syncthreads();
    }
    int run = tmp[tid] - s; // exclusive prefix
    for (int i = start; i < end; ++i) {
        rowptr[i] = run;
#pragma unroll
        for (int c = 0; c < 8; ++c) {
            int v = cnt8[(size_t)c * N + i];
            cnt8[(size_t)c * N + i] = run; // becomes cursor
            run += v;
        }
    }
    if (start < N && end == N) rowptr[N] = run;
}

__global__ void scatter_kernel(const int* __restrict__ src, const int* __restrict__ dst,
                               int* __restrict__ cursor8, int* __restrict__ ssrc,
                               int E, int Etot, int N) {
    int e = blockIdx.x * blockDim.x + threadIdx.x;
    if (e >= Etot) return;
    int c = blockIdx.x & 7;
    int s = (e < E) ? src[e] : (e - E);
    int d = (e < E) ? dst[e] : (e - E);
    int pos = atomicAdd(cursor8 + (size_t)c * N + d, 1);
    ssrc[pos] = s;
}

// ---------------- GAT aggregation: one wave per dst node, no atomics ----------------
__global__ void gat_agg(const int* __restrict__ rowptr, const int* __restrict__ ssrc,
                        const float* __restrict__ al_s, const float* __restrict__ al_d,
                        const float* __restrict__ h, float* __restrict__ out, int N) {
    int w = (blockIdx.x * blockDim.x + threadIdx.x) >> 6;
    int lane = threadIdx.x & 63;
    if (w >= N) return;
    int beg = rowptr[w], end = rowptr[w + 1];
    float ald = al_d[w];
    // pass 1: lane-parallel segment max
    float m = -1e30f;
    for (int e = beg + lane; e < end; e += 64) {
        float a = al_s[ssrc[e]] + ald;
        a = (a > 0.f) ? a : 0.2f * a;
        m = fmaxf(m, a);
    }
    for (int off = 32; off; off >>= 1) m = fmaxf(m, __shfl_xor(m, off));
    // pass 2: chunked — lane-parallel exp, feature-parallel gather via register broadcast
    float ss = 0.f, acc0 = 0.f, acc1 = 0.f;
    for (int base = beg; base < end; base += 64) {
        int nch = min(64, end - base);
        int sv = 0;
        float ev = 0.f;
        if (base + lane < end) {
            sv = ssrc[base + lane];
            float a = al_s[sv] + ald;
            a = (a > 0.f) ? a : 0.2f * a;
            ev = __expf(a - m);
        }
        ss += ev;
        for (int j = 0; j < nch; ++j) {
            int svj = __shfl(sv, j);
            float evj = __shfl(ev, j);
            const float2 hv = *(const float2*)(h + (size_t)svj * H + lane * 2);
            acc0 += evj * hv.x;
            acc1 += evj * hv.y;
        }
    }
    for (int off = 32; off; off >>= 1) ss += __shfl_xor(ss, off);
    float inv = 1.f / (ss + 1e-16f);
    float2* op = (float2*)(out + (size_t)w * H);
    op[lane] = make_float2(acc0 * inv, acc1 * inv);
}

// ---------------- BN stats: per-feature sum & sumsq ----------------
__global__ void bn_stats(const float* __restrict__ y, float* __restrict__ accum, int N) {
    int f = threadIdx.x & 127;
    int half = threadIdx.x >> 7;
    float sum = 0.f, sumsq = 0.f;
    for (int n = blockIdx.x * 2 + half; n < N; n += gridDim.x * 2) {
        float v = y[(size_t)n * H + f];
        sum += v;
        sumsq += v * v;
    }
    __shared__ float ls[2][128], ls2[2][128];
    ls[half][f] = sum;
    ls2[half][f] = sumsq;
    __syncthreads();
    if (half == 0) {
        atomicAdd(accum + f, ls[0][f] + ls[1][f]);
        atomicAdd(accum + 128 + f, ls2[0][f] + ls2[1][f]);
    }
}

// ---------------- BN apply + relu + residual (in-place) ----------------
__global__ void bn_apply(float* __restrict__ y, const float* __restrict__ accum,
                         const float* __restrict__ g, const float* __restrict__ be,
                         const float* __restrict__ res, int N) {
    int i = blockIdx.x * blockDim.x + threadIdx.x;
    if (i >= N * H) return;
    int f = i & 127;
    float Ninv = 1.f / (float)N;
    float mu = accum[f] * Ninv;
    float var = accum[128 + f] * Ninv - mu * mu;
    float v = (y[i] - mu) * rsqrtf(var + 1e-5f) * g[f] + be[f];
    y[i] = fmaxf(v, 0.f) + res[i];
}

// ---------------- final fc2: [N,128] -> [N,16] ----------------
__global__ void fc2_kernel(const float* __restrict__ in, const float* __restrict__ w,
                           const float* __restrict__ b, float* __restrict__ out,
                           int N, int OUT) {
    __shared__ float wsm[16 * 132];
    for (int i = threadIdx.x; i < OUT * H; i += 256) {
        int o = i >> 7, k = i & 127;
        wsm[o * 132 + k] = w[i];
    }
    __syncthreads();
    int o = threadIdx.x & 15;
    int nn = threadIdx.x >> 4;
    int n = blockIdx.x * 16 + nn;
    if (n >= N || o >= OUT) return;
    const float* xr = in + (size_t)n * H;
    const float* wr = wsm + o * 132;
    float acc = b[o];
#pragma unroll 8
    for (int k = 0; k < H; k += 4) {
        acc += xr[k] * wr[k] + xr[k + 1] * wr[k + 1] + xr[k + 2] * wr[k + 2] + xr[k + 3] * wr[k + 3];
    }
    out[(size_t)n * OUT + o] = acc;
}

// ---------------- launch ----------------

extern "C" void kernel_launch(void* const* d_in, const int* in_sizes, int n_in,
                              void* d_out, int out_size, void* d_ws, size_t ws_size,
                              hipStream_t stream) {
    const float* x       = (const float*)d_in[0];
    const int*   ei      = (const int*)d_in[1];
    const float* sat_w   = (const float*)d_in[2];
    const float* sat_b   = (const float*)d_in[3];
    const float* neigh_w = (const float*)d_in[4];
    const float* neigh_b = (const float*)d_in[5];
    const float* fus_w   = (const float*)d_in[6];
    const float* fus_b   = (const float*)d_in[7];
    const float* w1      = (const float*)d_in[8];
    const float* as1     = (const float*)d_in[9];
    const float* ad1     = (const float*)d_in[10];
    const float* g1      = (const float*)d_in[12];
    const float* be1     = (const float*)d_in[13];
    const float* w2      = (const float*)d_in[14];
    const float* as2     = (const float*)d_in[15];
    const float* ad2     = (const float*)d_in[16];
    const float* g2      = (const float*)d_in[18];
    const float* be2     = (const float*)d_in[19];
    const float* fc1_w   = (const float*)d_in[20];
    const float* fc1_b   = (const float*)d_in[21];
    const float* fc2_w   = (const float*)d_in[22];
    const float* fc2_b   = (const float*)d_in[23];

    int N = in_sizes[0] / 64;
    int E = in_sizes[1] / 2;
    int Etot = E + N;
    int OUT = in_sizes[23];

    float* ws   = (float*)d_ws;
    float* h0    = ws;                      // N*H
    float* hA    = h0 + (size_t)N * H;      // N*H
    float* agg   = hA + (size_t)N * H;      // N*H
    float* al_s  = agg + (size_t)N * H;     // N
    float* al_d  = al_s + N;                // N
    float* accum = al_d + N;                // 256
    int* rowptr  = (int*)(accum + 256);     // N+1
    int* cnt8    = rowptr + (N + 1);        // 8N (becomes cursor8)
    int* ssrc    = cnt8 + (size_t)8 * N;    // Etot

    const int* srcp = ei;
    const int* dstp = ei + E;

    dim3 b256(256);
    int gEdge = (Etot + 255) / 256;
    int gGemm = (N + NPB - 1) / NPB;
    int gNH = (N * H + 255) / 256;
    int gWaveN = (N + 3) / 4;

    // ---- fuse ----
    fuse_kernel<<<N, 128, 0, stream>>>(x, sat_w, sat_b, neigh_w, neigh_b, fus_w, fus_b, h0, N);

    // ---- CSR build (shared by both layers) ----
    fill_u32<<<(8 * N + 255) / 256, b256, 0, stream>>>((unsigned*)cnt8, 0u, 8 * N);
    hist_kernel<<<gEdge, b256, 0, stream>>>(dstp, cnt8, E, Etot, N);
    scan_kernel<<<1, 1024, 0, stream>>>(cnt8, rowptr, N);
    scatter_kernel<<<gEdge, b256, 0, stream>>>(srcp, dstp, cnt8, ssrc, E, Etot, N);

    // ================= GAT layer 1 =================
    gemm128<<<gGemm, b256, 0, stream>>>(h0, w1, nullptr, 0, hA, N);
    attn_logits<<<gWaveN, b256, 0, stream>>>(hA, as1, ad1, al_s, al_d, N);
    fill_u32<<<1, 256, 0, stream>>>((unsigned*)accum, 0u, 256);
    gat_agg<<<gWaveN, b256, 0, stream>>>(rowptr, ssrc, al_s, al_d, hA, agg, N);
    bn_stats<<<512, b256, 0, stream>>>(agg, accum, N);
    bn_apply<<<gNH, b256, 0, stream>>>(agg, accum, g1, be1, h0, N);

    // ================= GAT layer 2 =================
    gemm128<<<gGemm, b256, 0, stream>>>(agg, w2, nullptr, 0, hA, N);
    attn_logits<<<gWaveN, b256, 0, stream>>>(hA, as2, ad2, al_s, al_d, N);
    fill_u32<<<1, 256, 0, stream>>>((unsigned*)accum, 0u, 256);
    gat_agg<<<gWaveN, b256, 0, stream>>>(rowptr, ssrc, al_s, al_d, hA, h0, N);
    bn_stats<<<512, b256, 0, stream>>>(h0, accum, N);
    bn_apply<<<gNH, b256, 0, stream>>>(h0, accum, g2, be2, agg, N);

    // ================= head =================
    gemm128<<<gGemm, b256, 0, stream>>>(h0, fc1_w, fc1_b, 1, hA, N);
    fc2_kernel<<<(N + 15) / 16, b256, 0, stream>>>(hA, fc2_w, fc2_b, (float*)d_out, N, OUT);
}

// Round 3
// 6591.202 us; speedup vs baseline: 1.3918x; 1.0916x over previous
//
#include <hip/hip_runtime.h>

#define H 128
#define SCB 256

__global__ void fill_u32(unsigned* __restrict__ p, unsigned v, int n) {
    int i = blockIdx.x * blockDim.x + threadIdx.x;
    if (i < n) p[i] = v;
}

// ---------------- fuse: sat/nei linear + gate ----------------
__global__ void fuse_kernel(const float* __restrict__ x,
                            const float* __restrict__ sat_w, const float* __restrict__ sat_b,
                            const float* __restrict__ neigh_w, const float* __restrict__ neigh_b,
                            const float* __restrict__ fus_w, const float* __restrict__ fus_b,
                            float* __restrict__ h0, int N) {
    int n = blockIdx.x;
    int f = threadIdx.x; // 0..127
    __shared__ float xs[64];
    __shared__ float red[128];
    if (f < 64) xs[f] = x[(size_t)n * 64 + f];
    __syncthreads();
    float s_acc = sat_b[f], n_acc = neigh_b[f];
#pragma unroll 8
    for (int k = 0; k < 32; ++k) {
        s_acc += xs[k] * sat_w[f * 32 + k];
        n_acc += xs[32 + k] * neigh_w[f * 32 + k];
    }
    float sat = fmaxf(s_acc, 0.f), nei = fmaxf(n_acc, 0.f);
    red[f] = sat * fus_w[f] + nei * fus_w[128 + f];
    __syncthreads();
    for (int off = 64; off > 0; off >>= 1) {
        if (f < off) red[f] += red[f + off];
        __syncthreads();
    }
    float gate = 1.f / (1.f + expf(-(red[0] + fus_b[0])));
    h0[(size_t)n * H + f] = gate * sat + (1.f - gate) * nei;
}

// ---------------- 128x128 GEMM ----------------
#define NPB 8
__global__ void gemm128(const float* __restrict__ in, const float* __restrict__ w,
                        const float* __restrict__ bias, int do_relu,
                        float* __restrict__ out, int N) {
    __shared__ float xs[NPB][H];
    int block0 = blockIdx.x * NPB;
    int t = threadIdx.x;
    for (int i = t; i < NPB * H; i += 256) {
        int nn = i >> 7, f = i & 127;
        int n = block0 + nn;
        xs[nn][f] = (n < N) ? in[(size_t)n * H + f] : 0.f;
    }
    __syncthreads();
    int col = t & 127;
    int half = t >> 7;
    float acc[4] = {0.f, 0.f, 0.f, 0.f};
    const float4* w4 = (const float4*)(w + (size_t)col * H);
    for (int k4 = 0; k4 < H / 4; ++k4) {
        float4 wv = w4[k4];
#pragma unroll
        for (int j = 0; j < 4; ++j) {
            float4 xv = ((const float4*)xs[half * 4 + j])[k4];
            acc[j] += wv.x * xv.x + wv.y * xv.y + wv.z * xv.z + wv.w * xv.w;
        }
    }
    float bv = bias ? bias[col] : 0.f;
#pragma unroll
    for (int j = 0; j < 4; ++j) {
        int n = block0 + half * 4 + j;
        if (n < N) {
            float v = acc[j] + bv;
            if (do_relu) v = fmaxf(v, 0.f);
            out[(size_t)n * H + col] = v;
        }
    }
}

// ---------------- attention logits per node (one wave per node) ----------------
__global__ void attn_logits(const float* __restrict__ h1,
                            const float* __restrict__ a_s, const float* __restrict__ a_d,
                            float* __restrict__ al_s, float* __restrict__ al_d, int N) {
    int wid = (blockIdx.x * blockDim.x + threadIdx.x) >> 6;
    int lane = threadIdx.x & 63;
    if (wid >= N) return;
    const float* hr = h1 + (size_t)wid * H;
    float h_lo = hr[lane], h_hi = hr[lane + 64];
    float ps = h_lo * a_s[lane] + h_hi * a_s[lane + 64];
    float pd = h_lo * a_d[lane] + h_hi * a_d[lane + 64];
    for (int off = 32; off > 0; off >>= 1) {
        ps += __shfl_down(ps, off);
        pd += __shfl_down(pd, off);
    }
    if (lane == 0) { al_s[wid] = ps; al_d[wid] = pd; }
}

// ---------------- CSR build: 8-copy histogram (XCD-localized atomics) ----------------
__global__ void hist_kernel(const int* __restrict__ dst, int* __restrict__ cnt8,
                            int E, int Etot, int N) {
    int e = blockIdx.x * blockDim.x + threadIdx.x;
    if (e >= Etot) return;
    int c = blockIdx.x & 7;
    int d = (e < E) ? dst[e] : (e - E);
    atomicAdd(cnt8 + (size_t)c * N + d, 1);
}

// coalesced 3-step scan
__global__ void scan_a(const int* __restrict__ cnt8, int* __restrict__ nodeoff,
                       int* __restrict__ blocksum, int N) {
    int i = blockIdx.x * SCB + threadIdx.x;
    int tot = 0;
    if (i < N) {
#pragma unroll
        for (int c = 0; c < 8; ++c) tot += cnt8[(size_t)c * N + i];
    }
    __shared__ int tmp[SCB];
    tmp[threadIdx.x] = tot;
    __syncthreads();
    for (int off = 1; off < SCB; off <<= 1) {
        int t = (threadIdx.x >= off) ? tmp[threadIdx.x - off] : 0;
        __syncthreads();
        tmp[threadIdx.x] += t;
        __syncthreads();
    }
    if (i < N) nodeoff[i] = tmp[threadIdx.x] - tot;
    if (threadIdx.x == SCB - 1) blocksum[blockIdx.x] = tmp[SCB - 1];
}

__global__ void scan_b(const int* __restrict__ blocksum, int* __restrict__ blockoff,
                       int* __restrict__ rowptrN, int NB) {
    __shared__ int tmp[1024];
    int t = threadIdx.x;
    int v = (t < NB) ? blocksum[t] : 0;
    tmp[t] = v;
    __syncthreads();
    for (int off = 1; off < 1024; off <<= 1) {
        int u = (t >= off) ? tmp[t - off] : 0;
        __syncthreads();
        tmp[t] += u;
        __syncthreads();
    }
    if (t < NB) blockoff[t] = tmp[t] - v;
    if (t == 1023) *rowptrN = tmp[1023];
}

__global__ void scan_c(int* __restrict__ cnt8, const int* __restrict__ nodeoff,
                       const int* __restrict__ blockoff, int* __restrict__ rowptr, int N) {
    int i = blockIdx.x * SCB + threadIdx.x;
    if (i >= N) return;
    int run = blockoff[blockIdx.x] + nodeoff[i];
    rowptr[i] = run;
#pragma unroll
    for (int c = 0; c < 8; ++c) {
        int v = cnt8[(size_t)c * N + i];
        cnt8[(size_t)c * N + i] = run; // becomes cursor
        run += v;
    }
}

__global__ void scatter_kernel(const int* __restrict__ src, const int* __restrict__ dst,
                               int* __restrict__ cursor8, int* __restrict__ ssrc,
                               int E, int Etot, int N) {
    int e = blockIdx.x * blockDim.x + threadIdx.x;
    if (e >= Etot) return;
    int c = blockIdx.x & 7;
    int s = (e < E) ? src[e] : (e - E);
    int d = (e < E) ? dst[e] : (e - E);
    int pos = atomicAdd(cursor8 + (size_t)c * N + d, 1);
    ssrc[pos] = s;
}

// ---------------- GAT aggregation: one wave per dst node, 8-deep prefetch ----------------
#define PF 8
__global__ void gat_agg(const int* __restrict__ rowptr, const int* __restrict__ ssrc,
                        const float* __restrict__ al_s, const float* __restrict__ al_d,
                        const float* __restrict__ h, float* __restrict__ out, int N) {
    __shared__ int s_sv[4][64];
    __shared__ float s_ev[4][64];
    int wiw = threadIdx.x >> 6; // wave in block
    int w = (blockIdx.x * blockDim.x + threadIdx.x) >> 6;
    int lane = threadIdx.x & 63;
    if (w >= N) return;
    int beg = rowptr[w], end = rowptr[w + 1];
    float ald = al_d[w];
    // pass 1: lane-parallel segment max
    float m = -1e30f;
    for (int e = beg + lane; e < end; e += 64) {
        float a = al_s[ssrc[e]] + ald;
        a = (a > 0.f) ? a : 0.2f * a;
        m = fmaxf(m, a);
    }
    for (int off = 32; off; off >>= 1) m = fmaxf(m, __shfl_xor(m, off));
    // pass 2: per 64-edge chunk: lane-parallel exp -> LDS; then 8-deep prefetched FMA
    float ss = 0.f, acc0 = 0.f, acc1 = 0.f;
    for (int base = beg; base < end; base += 64) {
        int nch = min(64, end - base);
        int sv = 0;
        float ev = 0.f;
        if (lane < nch) {
            sv = ssrc[base + lane];
            float a = al_s[sv] + ald;
            a = (a > 0.f) ? a : 0.2f * a;
            ev = __expf(a - m);
        }
        ss += ev;
        s_sv[wiw][lane] = sv;
        s_ev[wiw][lane] = ev;
        // wave-synchronous LDS (per-wave slice) — no barrier needed
        for (int j0 = 0; j0 < nch; j0 += PF) {
            int np = min(PF, nch - j0);
            float2 hv[PF];
#pragma unroll
            for (int jj = 0; jj < PF; ++jj) {
                if (jj < np) {
                    int svj = s_sv[wiw][j0 + jj];
                    hv[jj] = *(const float2*)(h + (size_t)svj * H + lane * 2);
                }
            }
#pragma unroll
            for (int jj = 0; jj < PF; ++jj) {
                if (jj < np) {
                    float evj = s_ev[wiw][j0 + jj];
                    acc0 += evj * hv[jj].x;
                    acc1 += evj * hv[jj].y;
                }
            }
        }
    }
    for (int off = 32; off; off >>= 1) ss += __shfl_xor(ss, off);
    float inv = 1.f / (ss + 1e-16f);
    ((float2*)(out + (size_t)w * H))[lane] = make_float2(acc0 * inv, acc1 * inv);
}

// ---------------- BN stats ----------------
__global__ void bn_stats(const float* __restrict__ y, float* __restrict__ accum, int N) {
    int f = threadIdx.x & 127;
    int half = threadIdx.x >> 7;
    float sum = 0.f, sumsq = 0.f;
    for (int n = blockIdx.x * 2 + half; n < N; n += gridDim.x * 2) {
        float v = y[(size_t)n * H + f];
        sum += v;
        sumsq += v * v;
    }
    __shared__ float ls[2][128], ls2[2][128];
    ls[half][f] = sum;
    ls2[half][f] = sumsq;
    __syncthreads();
    if (half == 0) {
        atomicAdd(accum + f, ls[0][f] + ls[1][f]);
        atomicAdd(accum + 128 + f, ls2[0][f] + ls2[1][f]);
    }
}

// ---------------- BN apply + relu + residual ----------------
__global__ void bn_apply(float* __restrict__ y, const float* __restrict__ accum,
                         const float* __restrict__ g, const float* __restrict__ be,
                         const float* __restrict__ res, int N) {
    int i = blockIdx.x * blockDim.x + threadIdx.x;
    if (i >= N * H) return;
    int f = i & 127;
    float Ninv = 1.f / (float)N;
    float mu = accum[f] * Ninv;
    float var = accum[128 + f] * Ninv - mu * mu;
    float v = (y[i] - mu) * rsqrtf(var + 1e-5f) * g[f] + be[f];
    y[i] = fmaxf(v, 0.f) + res[i];
}

// ---------------- final fc2 ----------------
__global__ void fc2_kernel(const float* __restrict__ in, const float* __restrict__ w,
                           const float* __restrict__ b, float* __restrict__ out,
                           int N, int OUT) {
    __shared__ float wsm[16 * 132];
    for (int i = threadIdx.x; i < OUT * H; i += 256) {
        int o = i >> 7, k = i & 127;
        wsm[o * 132 + k] = w[i];
    }
    __syncthreads();
    int o = threadIdx.x & 15;
    int nn = threadIdx.x >> 4;
    int n = blockIdx.x * 16 + nn;
    if (n >= N || o >= OUT) return;
    const float* xr = in + (size_t)n * H;
    const float* wr = wsm + o * 132;
    float acc = b[o];
#pragma unroll 8
    for (int k = 0; k < H; k += 4) {
        acc += xr[k] * wr[k] + xr[k + 1] * wr[k + 1] + xr[k + 2] * wr[k + 2] + xr[k + 3] * wr[k + 3];
    }
    out[(size_t)n * OUT + o] = acc;
}

// ---------------- launch ----------------

extern "C" void kernel_launch(void* const* d_in, const int* in_sizes, int n_in,
                              void* d_out, int out_size, void* d_ws, size_t ws_size,
                              hipStream_t stream) {
    const float* x       = (const float*)d_in[0];
    const int*   ei      = (const int*)d_in[1];
    const float* sat_w   = (const float*)d_in[2];
    const float* sat_b   = (const float*)d_in[3];
    const float* neigh_w = (const float*)d_in[4];
    const float* neigh_b = (const float*)d_in[5];
    const float* fus_w   = (const float*)d_in[6];
    const float* fus_b   = (const float*)d_in[7];
    const float* w1      = (const float*)d_in[8];
    const float* as1     = (const float*)d_in[9];
    const float* ad1     = (const float*)d_in[10];
    const float* g1      = (const float*)d_in[12];
    const float* be1     = (const float*)d_in[13];
    const float* w2      = (const float*)d_in[14];
    const float* as2     = (const float*)d_in[15];
    const float* ad2     = (const float*)d_in[16];
    const float* g2      = (const float*)d_in[18];
    const float* be2     = (const float*)d_in[19];
    const float* fc1_w   = (const float*)d_in[20];
    const float* fc1_b   = (const float*)d_in[21];
    const float* fc2_w   = (const float*)d_in[22];
    const float* fc2_b   = (const float*)d_in[23];

    int N = in_sizes[0] / 64;
    int E = in_sizes[1] / 2;
    int Etot = E + N;
    int OUT = in_sizes[23];
    int NB = (N + SCB - 1) / SCB;

    float* ws    = (float*)d_ws;
    float* h0    = ws;                      // N*H
    float* hA    = h0 + (size_t)N * H;      // N*H
    float* agg   = hA + (size_t)N * H;      // N*H
    float* al_s  = agg + (size_t)N * H;     // N
    float* al_d  = al_s + N;                // N
    float* accum = al_d + N;                // 256
    int* rowptr  = (int*)(accum + 256);     // N+1
    int* cnt8    = rowptr + (N + 1);        // 8N (becomes cursor8)
    int* nodeoff = cnt8 + (size_t)8 * N;    // N
    int* blocksum= nodeoff + N;             // NB
    int* blockoff= blocksum + NB;           // NB
    int* ssrc    = blockoff + NB;           // Etot

    const int* srcp = ei;
    const int* dstp = ei + E;

    dim3 b256(256);
    int gEdge = (Etot + 255) / 256;
    int gGemm = (N + NPB - 1) / NPB;
    int gNH = (N * H + 255) / 256;
    int gWaveN = (N + 3) / 4;

    // ---- fuse ----
    fuse_kernel<<<N, 128, 0, stream>>>(x, sat_w, sat_b, neigh_w, neigh_b, fus_w, fus_b, h0, N);

    // ---- CSR build (shared by both layers) ----
    fill_u32<<<(8 * N + 255) / 256, b256, 0, stream>>>((unsigned*)cnt8, 0u, 8 * N);
    hist_kernel<<<gEdge, b256, 0, stream>>>(dstp, cnt8, E, Etot, N);
    scan_a<<<NB, SCB, 0, stream>>>(cnt8, nodeoff, blocksum, N);
    scan_b<<<1, 1024, 0, stream>>>(blocksum, blockoff, rowptr + N, NB);
    scan_c<<<NB, SCB, 0, stream>>>(cnt8, nodeoff, blockoff, rowptr, N);
    scatter_kernel<<<gEdge, b256, 0, stream>>>(srcp, dstp, cnt8, ssrc, E, Etot, N);

    // ================= GAT layer 1 =================
    gemm128<<<gGemm, b256, 0, stream>>>(h0, w1, nullptr, 0, hA, N);
    attn_logits<<<gWaveN, b256, 0, stream>>>(hA, as1, ad1, al_s, al_d, N);
    fill_u32<<<1, 256, 0, stream>>>((unsigned*)accum, 0u, 256);
    gat_agg<<<gWaveN, b256, 0, stream>>>(rowptr, ssrc, al_s, al_d, hA, agg, N);
    bn_stats<<<512, b256, 0, stream>>>(agg, accum, N);
    bn_apply<<<gNH, b256, 0, stream>>>(agg, accum, g1, be1, h0, N);

    // ================= GAT layer 2 =================
    gemm128<<<gGemm, b256, 0, stream>>>(agg, w2, nullptr, 0, hA, N);
    attn_logits<<<gWaveN, b256, 0, stream>>>(hA, as2, ad2, al_s, al_d, N);
    fill_u32<<<1, 256, 0, stream>>>((unsigned*)accum, 0u, 256);
    gat_agg<<<gWaveN, b256, 0, stream>>>(rowptr, ssrc, al_s, al_d, hA, h0, N);
    bn_stats<<<512, b256, 0, stream>>>(h0, accum, N);
    bn_apply<<<gNH, b256, 0, stream>>>(h0, accum, g2, be2, agg, N);

    // ================= head =================
    gemm128<<<gGemm, b256, 0, stream>>>(h0, fc1_w, fc1_b, 1, hA, N);
    fc2_kernel<<<(N + 15) / 16, b256, 0, stream>>>(hA, fc2_w, fc2_b, (float*)d_out, N, OUT);
}

// Round 4
// 980.889 us; speedup vs baseline: 9.3521x; 6.7196x over previous
//
#include <hip/hip_runtime.h>

#define H 128

__global__ void fill_u32(unsigned* __restrict__ p, unsigned v, int n) {
    int i = blockIdx.x * blockDim.x + threadIdx.x;
    if (i < n) p[i] = v;
}

// ---------------- fuse: one wave per node, weights in padded LDS ----------------
__global__ void fuse_kernel(const float* __restrict__ x,
                            const float* __restrict__ sat_w, const float* __restrict__ sat_b,
                            const float* __restrict__ neigh_w, const float* __restrict__ neigh_b,
                            const float* __restrict__ fus_w, const float* __restrict__ fus_b,
                            float* __restrict__ h0, int N) {
    __shared__ float swei[128 * 33];
    __shared__ float nwei[128 * 33];
    int tid = threadIdx.x;
    // stage weights once per block: coalesced global, 2-way (free) LDS banks
    for (int i = tid; i < 128 * 32; i += 256) {
        int r = i >> 5, k = i & 31;
        swei[r * 33 + k] = sat_w[i];
        nwei[r * 33 + k] = neigh_w[i];
    }
    __syncthreads();
    int lane = tid & 63;
    int wv = tid >> 6;
    int nwaves = gridDim.x * 4;
    // per-lane constants (feature l = lane, and lane+64)
    float sb0 = sat_b[lane], sb1 = sat_b[lane + 64];
    float nb0 = neigh_b[lane], nb1 = neigh_b[lane + 64];
    float fw0 = fus_w[lane], fw1 = fus_w[lane + 64];
    float fw2 = fus_w[128 + lane], fw3 = fus_w[192 + lane];
    float fb = fus_b[0];
    for (int node = blockIdx.x * 4 + wv; node < N; node += nwaves) {
        float xv = x[(size_t)node * 64 + lane]; // coalesced 256B per wave
        float a0 = sb0, a1 = sb1, b0 = nb0, b1 = nb1;
#pragma unroll 8
        for (int k = 0; k < 32; ++k) {
            float xk = __shfl(xv, k);
            a0 += xk * swei[lane * 33 + k];
            a1 += xk * swei[(lane + 64) * 33 + k];
            float yk = __shfl(xv, 32 + k);
            b0 += yk * nwei[lane * 33 + k];
            b1 += yk * nwei[(lane + 64) * 33 + k];
        }
        float s0 = fmaxf(a0, 0.f), s1 = fmaxf(a1, 0.f);
        float n0 = fmaxf(b0, 0.f), n1 = fmaxf(b1, 0.f);
        float part = s0 * fw0 + s1 * fw1 + n0 * fw2 + n1 * fw3;
        for (int off = 32; off; off >>= 1) part += __shfl_xor(part, off);
        float g = 1.f / (1.f + __expf(-(part + fb)));
        h0[(size_t)node * H + lane] = g * s0 + (1.f - g) * n0;
        h0[(size_t)node * H + lane + 64] = g * s1 + (1.f - g) * n1;
    }
}

// ---------------- 128x128 GEMM: 64-node tile in pad-129 LDS, wave-uniform w ----------------
__global__ void gemm128(const float* __restrict__ in, const float* __restrict__ w,
                        const float* __restrict__ bias, int do_relu,
                        float* __restrict__ out, int N) {
    __shared__ float xl[64 * 129];
    int tid = threadIdx.x;
    int base = blockIdx.x * 64;
    for (int i = tid; i < 64 * 128; i += 256) {
        int n = i >> 7, k = i & 127;
        int gn = base + n;
        xl[n * 129 + k] = (gn < N) ? in[(size_t)gn * 128 + k] : 0.f;
    }
    __syncthreads();
    int lane = tid & 63;
    int wv = __builtin_amdgcn_readfirstlane(tid >> 6); // wave-uniform -> scalar w loads
    int node = base + lane;
    int xb = lane * 129;
    for (int c = 0; c < 32; ++c) {
        int col = wv * 32 + c;
        const float* wr = w + (size_t)col * 128;
        float acc = 0.f;
#pragma unroll 16
        for (int k = 0; k < 128; ++k) acc += xl[xb + k] * wr[k];
        if (node < N) {
            float v = acc + (bias ? bias[col] : 0.f);
            if (do_relu) v = fmaxf(v, 0.f);
            out[(size_t)node * H + col] = v;
        }
    }
}

// ---------------- attention logits per node (one wave per node) ----------------
__global__ void attn_logits(const float* __restrict__ h1,
                            const float* __restrict__ a_s, const float* __restrict__ a_d,
                            float* __restrict__ al_s, float* __restrict__ al_d, int N) {
    int wid = (blockIdx.x * blockDim.x + threadIdx.x) >> 6;
    int lane = threadIdx.x & 63;
    if (wid >= N) return;
    const float* hr = h1 + (size_t)wid * H;
    float h_lo = hr[lane], h_hi = hr[lane + 64];
    float ps = h_lo * a_s[lane] + h_hi * a_s[lane + 64];
    float pd = h_lo * a_d[lane] + h_hi * a_d[lane + 64];
    for (int off = 32; off > 0; off >>= 1) {
        ps += __shfl_down(ps, off);
        pd += __shfl_down(pd, off);
    }
    if (lane == 0) { al_s[wid] = ps; al_d[wid] = pd; }
}

// ---------------- CSR build ----------------
#define SCB 256
__global__ void hist_kernel(const int* __restrict__ dst, int* __restrict__ cnt8,
                            int E, int Etot, int N) {
    int e = blockIdx.x * blockDim.x + threadIdx.x;
    if (e >= Etot) return;
    int c = blockIdx.x & 7;
    int d = (e < E) ? dst[e] : (e - E);
    atomicAdd(cnt8 + (size_t)c * N + d, 1);
}

__global__ void scan_a(const int* __restrict__ cnt8, int* __restrict__ nodeoff,
                       int* __restrict__ blocksum, int N) {
    int i = blockIdx.x * SCB + threadIdx.x;
    int tot = 0;
    if (i < N) {
#pragma unroll
        for (int c = 0; c < 8; ++c) tot += cnt8[(size_t)c * N + i];
    }
    __shared__ int tmp[SCB];
    tmp[threadIdx.x] = tot;
    __syncthreads();
    for (int off = 1; off < SCB; off <<= 1) {
        int t = (threadIdx.x >= off) ? tmp[threadIdx.x - off] : 0;
        __syncthreads();
        tmp[threadIdx.x] += t;
        __syncthreads();
    }
    if (i < N) nodeoff[i] = tmp[threadIdx.x] - tot;
    if (threadIdx.x == SCB - 1) blocksum[blockIdx.x] = tmp[SCB - 1];
}

__global__ void scan_b(const int* __restrict__ blocksum, int* __restrict__ blockoff,
                       int* __restrict__ rowptrN, int NB) {
    __shared__ int tmp[1024];
    int t = threadIdx.x;
    int v = (t < NB) ? blocksum[t] : 0;
    tmp[t] = v;
    __syncthreads();
    for (int off = 1; off < 1024; off <<= 1) {
        int u = (t >= off) ? tmp[t - off] : 0;
        __syncthreads();
        tmp[t] += u;
        __syncthreads();
    }
    if (t < NB) blockoff[t] = tmp[t] - v;
    if (t == 1023) *rowptrN = tmp[1023];
}

__global__ void scan_c(int* __restrict__ cnt8, const int* __restrict__ nodeoff,
                       const int* __restrict__ blockoff, int* __restrict__ rowptr, int N) {
    int i = blockIdx.x * SCB + threadIdx.x;
    if (i >= N) return;
    int run = blockoff[blockIdx.x] + nodeoff[i];
    rowptr[i] = run;
#pragma unroll
    for (int c = 0; c < 8; ++c) {
        int v = cnt8[(size_t)c * N + i];
        cnt8[(size_t)c * N + i] = run; // becomes cursor
        run += v;
    }
}

__global__ void scatter_kernel(const int* __restrict__ src, const int* __restrict__ dst,
                               int* __restrict__ cursor8, int* __restrict__ ssrc,
                               int E, int Etot, int N) {
    int e = blockIdx.x * blockDim.x + threadIdx.x;
    if (e >= Etot) return;
    int c = blockIdx.x & 7;
    int s = (e < E) ? src[e] : (e - E);
    int d = (e < E) ? dst[e] : (e - E);
    int pos = atomicAdd(cursor8 + (size_t)c * N + d, 1);
    ssrc[pos] = s;
}

// ---------------- GAT aggregation: one wave per dst node, 8-deep prefetch ----------------
#define PF 8
__global__ void gat_agg(const int* __restrict__ rowptr, const int* __restrict__ ssrc,
                        const float* __restrict__ al_s, const float* __restrict__ al_d,
                        const float* __restrict__ h, float* __restrict__ out, int N) {
    __shared__ int s_sv[4][64];
    __shared__ float s_ev[4][64];
    int wiw = threadIdx.x >> 6;
    int w = (blockIdx.x * blockDim.x + threadIdx.x) >> 6;
    int lane = threadIdx.x & 63;
    if (w >= N) return;
    int beg = rowptr[w], end = rowptr[w + 1];
    float ald = al_d[w];
    float m = -1e30f;
    for (int e = beg + lane; e < end; e += 64) {
        float a = al_s[ssrc[e]] + ald;
        a = (a > 0.f) ? a : 0.2f * a;
        m = fmaxf(m, a);
    }
    for (int off = 32; off; off >>= 1) m = fmaxf(m, __shfl_xor(m, off));
    float ss = 0.f, acc0 = 0.f, acc1 = 0.f;
    for (int base = beg; base < end; base += 64) {
        int nch = min(64, end - base);
        int sv = 0;
        float ev = 0.f;
        if (lane < nch) {
            sv = ssrc[base + lane];
            float a = al_s[sv] + ald;
            a = (a > 0.f) ? a : 0.2f * a;
            ev = __expf(a - m);
        }
        ss += ev;
        s_sv[wiw][lane] = sv;
        s_ev[wiw][lane] = ev;
        for (int j0 = 0; j0 < nch; j0 += PF) {
            int np = min(PF, nch - j0);
            float2 hv[PF];
#pragma unroll
            for (int jj = 0; jj < PF; ++jj) {
                if (jj < np) {
                    int svj = s_sv[wiw][j0 + jj];
                    hv[jj] = *(const float2*)(h + (size_t)svj * H + lane * 2);
                }
            }
#pragma unroll
            for (int jj = 0; jj < PF; ++jj) {
                if (jj < np) {
                    float evj = s_ev[wiw][j0 + jj];
                    acc0 += evj * hv[jj].x;
                    acc1 += evj * hv[jj].y;
                }
            }
        }
    }
    for (int off = 32; off; off >>= 1) ss += __shfl_xor(ss, off);
    float inv = 1.f / (ss + 1e-16f);
    ((float2*)(out + (size_t)w * H))[lane] = make_float2(acc0 * inv, acc1 * inv);
}

// ---------------- BN stats ----------------
__global__ void bn_stats(const float* __restrict__ y, float* __restrict__ accum, int N) {
    int f = threadIdx.x & 127;
    int half = threadIdx.x >> 7;
    float sum = 0.f, sumsq = 0.f;
    for (int n = blockIdx.x * 2 + half; n < N; n += gridDim.x * 2) {
        float v = y[(size_t)n * H + f];
        sum += v;
        sumsq += v * v;
    }
    __shared__ float ls[2][128], ls2[2][128];
    ls[half][f] = sum;
    ls2[half][f] = sumsq;
    __syncthreads();
    if (half == 0) {
        atomicAdd(accum + f, ls[0][f] + ls[1][f]);
        atomicAdd(accum + 128 + f, ls2[0][f] + ls2[1][f]);
    }
}

// ---------------- BN apply + relu + residual ----------------
__global__ void bn_apply(float* __restrict__ y, const float* __restrict__ accum,
                         const float* __restrict__ g, const float* __restrict__ be,
                         const float* __restrict__ res, int N) {
    int i = blockIdx.x * blockDim.x + threadIdx.x;
    if (i >= N * H) return;
    int f = i & 127;
    float Ninv = 1.f / (float)N;
    float mu = accum[f] * Ninv;
    float var = accum[128 + f] * Ninv - mu * mu;
    float v = (y[i] - mu) * rsqrtf(var + 1e-5f) * g[f] + be[f];
    y[i] = fmaxf(v, 0.f) + res[i];
}

// ---------------- final fc2 ----------------
__global__ void fc2_kernel(const float* __restrict__ in, const float* __restrict__ w,
                           const float* __restrict__ b, float* __restrict__ out,
                           int N, int OUT) {
    __shared__ float wsm[16 * 132];
    for (int i = threadIdx.x; i < OUT * H; i += 256) {
        int o = i >> 7, k = i & 127;
        wsm[o * 132 + k] = w[i];
    }
    __syncthreads();
    int o = threadIdx.x & 15;
    int nn = threadIdx.x >> 4;
    int n = blockIdx.x * 16 + nn;
    if (n >= N || o >= OUT) return;
    const float* xr = in + (size_t)n * H;
    const float* wr = wsm + o * 132;
    float acc = b[o];
#pragma unroll 8
    for (int k = 0; k < H; k += 4) {
        acc += xr[k] * wr[k] + xr[k + 1] * wr[k + 1] + xr[k + 2] * wr[k + 2] + xr[k + 3] * wr[k + 3];
    }
    out[(size_t)n * OUT + o] = acc;
}

// ---------------- launch ----------------

extern "C" void kernel_launch(void* const* d_in, const int* in_sizes, int n_in,
                              void* d_out, int out_size, void* d_ws, size_t ws_size,
                              hipStream_t stream) {
    const float* x       = (const float*)d_in[0];
    const int*   ei      = (const int*)d_in[1];
    const float* sat_w   = (const float*)d_in[2];
    const float* sat_b   = (const float*)d_in[3];
    const float* neigh_w = (const float*)d_in[4];
    const float* neigh_b = (const float*)d_in[5];
    const float* fus_w   = (const float*)d_in[6];
    const float* fus_b   = (const float*)d_in[7];
    const float* w1      = (const float*)d_in[8];
    const float* as1     = (const float*)d_in[9];
    const float* ad1     = (const float*)d_in[10];
    const float* g1      = (const float*)d_in[12];
    const float* be1     = (const float*)d_in[13];
    const float* w2      = (const float*)d_in[14];
    const float* as2     = (const float*)d_in[15];
    const float* ad2     = (const float*)d_in[16];
    const float* g2      = (const float*)d_in[18];
    const float* be2     = (const float*)d_in[19];
    const float* fc1_w   = (const float*)d_in[20];
    const float* fc1_b   = (const float*)d_in[21];
    const float* fc2_w   = (const float*)d_in[22];
    const float* fc2_b   = (const float*)d_in[23];

    int N = in_sizes[0] / 64;
    int E = in_sizes[1] / 2;
    int Etot = E + N;
    int OUT = in_sizes[23];
    int NB = (N + SCB - 1) / SCB;

    float* ws    = (float*)d_ws;
    float* h0    = ws;                      // N*H
    float* hA    = h0 + (size_t)N * H;      // N*H
    float* agg   = hA + (size_t)N * H;      // N*H
    float* al_s  = agg + (size_t)N * H;     // N
    float* al_d  = al_s + N;                // N
    float* accum = al_d + N;                // 256
    int* rowptr  = (int*)(accum + 256);     // N+1
    int* cnt8    = rowptr + (N + 1);        // 8N (becomes cursor8)
    int* nodeoff = cnt8 + (size_t)8 * N;    // N
    int* blocksum= nodeoff + N;             // NB
    int* blockoff= blocksum + NB;           // NB
    int* ssrc    = blockoff + NB;           // Etot

    const int* srcp = ei;
    const int* dstp = ei + E;

    dim3 b256(256);
    int gEdge = (Etot + 255) / 256;
    int gGemm = (N + 63) / 64;
    int gNH = (N * H + 255) / 256;
    int gWaveN = (N + 3) / 4;

    // ---- fuse ----
    fuse_kernel<<<2048, b256, 0, stream>>>(x, sat_w, sat_b, neigh_w, neigh_b, fus_w, fus_b, h0, N);

    // ---- CSR build (shared by both layers) ----
    fill_u32<<<(8 * N + 255) / 256, b256, 0, stream>>>((unsigned*)cnt8, 0u, 8 * N);
    hist_kernel<<<gEdge, b256, 0, stream>>>(dstp, cnt8, E, Etot, N);
    scan_a<<<NB, SCB, 0, stream>>>(cnt8, nodeoff, blocksum, N);
    scan_b<<<1, 1024, 0, stream>>>(blocksum, blockoff, rowptr + N, NB);
    scan_c<<<NB, SCB, 0, stream>>>(cnt8, nodeoff, blockoff, rowptr, N);
    scatter_kernel<<<gEdge, b256, 0, stream>>>(srcp, dstp, cnt8, ssrc, E, Etot, N);

    // ================= GAT layer 1 =================
    gemm128<<<gGemm, b256, 0, stream>>>(h0, w1, nullptr, 0, hA, N);
    attn_logits<<<gWaveN, b256, 0, stream>>>(hA, as1, ad1, al_s, al_d, N);
    fill_u32<<<1, 256, 0, stream>>>((unsigned*)accum, 0u, 256);
    gat_agg<<<gWaveN, b256, 0, stream>>>(rowptr, ssrc, al_s, al_d, hA, agg, N);
    bn_stats<<<512, b256, 0, stream>>>(agg, accum, N);
    bn_apply<<<gNH, b256, 0, stream>>>(agg, accum, g1, be1, h0, N);

    // ================= GAT layer 2 =================
    gemm128<<<gGemm, b256, 0, stream>>>(agg, w2, nullptr, 0, hA, N);
    attn_logits<<<gWaveN, b256, 0, stream>>>(hA, as2, ad2, al_s, al_d, N);
    fill_u32<<<1, 256, 0, stream>>>((unsigned*)accum, 0u, 256);
    gat_agg<<<gWaveN, b256, 0, stream>>>(rowptr, ssrc, al_s, al_d, hA, h0, N);
    bn_stats<<<512, b256, 0, stream>>>(h0, accum, N);
    bn_apply<<<gNH, b256, 0, stream>>>(h0, accum, g2, be2, agg, N);

    // ================= head =================
    gemm128<<<gGemm, b256, 0, stream>>>(h0, fc1_w, fc1_b, 1, hA, N);
    fc2_kernel<<<(N + 15) / 16, b256, 0, stream>>>(hA, fc2_w, fc2_b, (float*)d_out, N, OUT);
}

// Round 5
// 810.686 us; speedup vs baseline: 11.3155x; 1.2099x over previous
//
#include <hip/hip_runtime.h>

#define H 128

__global__ void fill_u32(unsigned* __restrict__ p, unsigned v, int n) {
    int i = blockIdx.x * blockDim.x + threadIdx.x;
    if (i < n) p[i] = v;
}

// ---------------- fuse: one wave per node, weights in padded LDS ----------------
__global__ void fuse_kernel(const float* __restrict__ x,
                            const float* __restrict__ sat_w, const float* __restrict__ sat_b,
                            const float* __restrict__ neigh_w, const float* __restrict__ neigh_b,
                            const float* __restrict__ fus_w, const float* __restrict__ fus_b,
                            float* __restrict__ h0, int N) {
    __shared__ float swei[128 * 33];
    __shared__ float nwei[128 * 33];
    int tid = threadIdx.x;
    for (int i = tid; i < 128 * 32; i += 256) {
        int r = i >> 5, k = i & 31;
        swei[r * 33 + k] = sat_w[i];
        nwei[r * 33 + k] = neigh_w[i];
    }
    __syncthreads();
    int lane = tid & 63;
    int wv = tid >> 6;
    int nwaves = gridDim.x * 4;
    float sb0 = sat_b[lane], sb1 = sat_b[lane + 64];
    float nb0 = neigh_b[lane], nb1 = neigh_b[lane + 64];
    float fw0 = fus_w[lane], fw1 = fus_w[lane + 64];
    float fw2 = fus_w[128 + lane], fw3 = fus_w[192 + lane];
    float fb = fus_b[0];
    for (int node = blockIdx.x * 4 + wv; node < N; node += nwaves) {
        float xv = x[(size_t)node * 64 + lane];
        float a0 = sb0, a1 = sb1, b0 = nb0, b1 = nb1;
#pragma unroll 8
        for (int k = 0; k < 32; ++k) {
            float xk = __shfl(xv, k);
            a0 += xk * swei[lane * 33 + k];
            a1 += xk * swei[(lane + 64) * 33 + k];
            float yk = __shfl(xv, 32 + k);
            b0 += yk * nwei[lane * 33 + k];
            b1 += yk * nwei[(lane + 64) * 33 + k];
        }
        float s0 = fmaxf(a0, 0.f), s1 = fmaxf(a1, 0.f);
        float n0 = fmaxf(b0, 0.f), n1 = fmaxf(b1, 0.f);
        float part = s0 * fw0 + s1 * fw1 + n0 * fw2 + n1 * fw3;
        for (int off = 32; off; off >>= 1) part += __shfl_xor(part, off);
        float g = 1.f / (1.f + __expf(-(part + fb)));
        h0[(size_t)node * H + lane] = g * s0 + (1.f - g) * n0;
        h0[(size_t)node * H + lane + 64] = g * s1 + (1.f - g) * n1;
    }
}

// ---------------- 128x128 GEMM: reg-accumulated cols + coalesced write phase ----------------
__global__ void gemm128(const float* __restrict__ in, const float* __restrict__ w,
                        const float* __restrict__ bias, int do_relu,
                        float* __restrict__ out, int N) {
    __shared__ float xl[64 * 129];
    int tid = threadIdx.x;
    int base = blockIdx.x * 64;
    for (int i = tid; i < 64 * 128; i += 256) {
        int n = i >> 7, k = i & 127;
        int gn = base + n;
        xl[n * 129 + k] = (gn < N) ? in[(size_t)gn * 128 + k] : 0.f;
    }
    __syncthreads();
    int lane = tid & 63;
    int wv = __builtin_amdgcn_readfirstlane(tid >> 6); // wave-uniform -> scalar w loads
    int xb = lane * 129;
    float accs[32];
    for (int cb = 0; cb < 4; ++cb) {
        float acc[8] = {0.f, 0.f, 0.f, 0.f, 0.f, 0.f, 0.f, 0.f};
        const float* wr = w + (size_t)(wv * 32 + cb * 8) * 128;
#pragma unroll 4
        for (int k = 0; k < 128; ++k) {
            float xv = xl[xb + k];
#pragma unroll
            for (int j = 0; j < 8; ++j) acc[j] += xv * wr[j * 128 + k];
        }
#pragma unroll
        for (int j = 0; j < 8; ++j) {
            float v = acc[j] + (bias ? bias[wv * 32 + cb * 8 + j] : 0.f);
            if (do_relu) v = fmaxf(v, 0.f);
            accs[cb * 8 + j] = v;
        }
    }
    // stage results to LDS (reuse xl), then fully coalesced global write
    __syncthreads();
#pragma unroll
    for (int c = 0; c < 32; ++c) xl[xb + wv * 32 + c] = accs[c];
    __syncthreads();
    for (int i = tid; i < 64 * 128; i += 256) {
        int n = i >> 7, k = i & 127;
        int gn = base + n;
        if (gn < N) out[(size_t)gn * H + k] = xl[n * 129 + k];
    }
}

// ---------------- attention logits per node (one wave per node) ----------------
__global__ void attn_logits(const float* __restrict__ h1,
                            const float* __restrict__ a_s, const float* __restrict__ a_d,
                            float* __restrict__ al_s, float* __restrict__ al_d, int N) {
    int wid = (blockIdx.x * blockDim.x + threadIdx.x) >> 6;
    int lane = threadIdx.x & 63;
    if (wid >= N) return;
    const float* hr = h1 + (size_t)wid * H;
    float h_lo = hr[lane], h_hi = hr[lane + 64];
    float ps = h_lo * a_s[lane] + h_hi * a_s[lane + 64];
    float pd = h_lo * a_d[lane] + h_hi * a_d[lane + 64];
    for (int off = 32; off > 0; off >>= 1) {
        ps += __shfl_down(ps, off);
        pd += __shfl_down(pd, off);
    }
    if (lane == 0) { al_s[wid] = ps; al_d[wid] = pd; }
}

// ---------------- CSR build ----------------
#define SCB 256
__global__ void hist_kernel(const int* __restrict__ dst, int* __restrict__ cnt8,
                            int E, int Etot, int N) {
    int e = blockIdx.x * blockDim.x + threadIdx.x;
    if (e >= Etot) return;
    int c = blockIdx.x & 7;
    int d = (e < E) ? dst[e] : (e - E);
    atomicAdd(cnt8 + (size_t)c * N + d, 1);
}

__global__ void scan_a(const int* __restrict__ cnt8, int* __restrict__ nodeoff,
                       int* __restrict__ blocksum, int N) {
    int i = blockIdx.x * SCB + threadIdx.x;
    int tot = 0;
    if (i < N) {
#pragma unroll
        for (int c = 0; c < 8; ++c) tot += cnt8[(size_t)c * N + i];
    }
    __shared__ int tmp[SCB];
    tmp[threadIdx.x] = tot;
    __syncthreads();
    for (int off = 1; off < SCB; off <<= 1) {
        int t = (threadIdx.x >= off) ? tmp[threadIdx.x - off] : 0;
        __syncthreads();
        tmp[threadIdx.x] += t;
        __syncthreads();
    }
    if (i < N) nodeoff[i] = tmp[threadIdx.x] - tot;
    if (threadIdx.x == SCB - 1) blocksum[blockIdx.x] = tmp[SCB - 1];
}

__global__ void scan_b(const int* __restrict__ blocksum, int* __restrict__ blockoff,
                       int* __restrict__ rowptrN, int NB) {
    __shared__ int tmp[1024];
    int t = threadIdx.x;
    int v = (t < NB) ? blocksum[t] : 0;
    tmp[t] = v;
    __syncthreads();
    for (int off = 1; off < 1024; off <<= 1) {
        int u = (t >= off) ? tmp[t - off] : 0;
        __syncthreads();
        tmp[t] += u;
        __syncthreads();
    }
    if (t < NB) blockoff[t] = tmp[t] - v;
    if (t == 1023) *rowptrN = tmp[1023];
}

__global__ void scan_c(int* __restrict__ cnt8, const int* __restrict__ nodeoff,
                       const int* __restrict__ blockoff, int* __restrict__ rowptr, int N) {
    int i = blockIdx.x * SCB + threadIdx.x;
    if (i >= N) return;
    int run = blockoff[blockIdx.x] + nodeoff[i];
    rowptr[i] = run;
#pragma unroll
    for (int c = 0; c < 8; ++c) {
        int v = cnt8[(size_t)c * N + i];
        cnt8[(size_t)c * N + i] = run; // becomes cursor
        run += v;
    }
}

__global__ void scatter_kernel(const int* __restrict__ src, const int* __restrict__ dst,
                               int* __restrict__ cursor8, int* __restrict__ ssrc,
                               int E, int Etot, int N) {
    int e = blockIdx.x * blockDim.x + threadIdx.x;
    if (e >= Etot) return;
    int c = blockIdx.x & 7;
    int s = (e < E) ? src[e] : (e - E);
    int d = (e < E) ? dst[e] : (e - E);
    int pos = atomicAdd(cursor8 + (size_t)c * N + d, 1);
    ssrc[pos] = s;
}

// ---------------- GAT aggregation: one wave per dst node, 8-deep prefetch ----------------
#define PF 8
__global__ void gat_agg(const int* __restrict__ rowptr, const int* __restrict__ ssrc,
                        const float* __restrict__ al_s, const float* __restrict__ al_d,
                        const float* __restrict__ h, float* __restrict__ out, int N) {
    __shared__ int s_sv[4][64];
    __shared__ float s_ev[4][64];
    int wiw = threadIdx.x >> 6;
    int w = (blockIdx.x * blockDim.x + threadIdx.x) >> 6;
    int lane = threadIdx.x & 63;
    if (w >= N) return;
    int beg = rowptr[w], end = rowptr[w + 1];
    float ald = al_d[w];
    float m = -1e30f;
    for (int e = beg + lane; e < end; e += 64) {
        float a = al_s[ssrc[e]] + ald;
        a = (a > 0.f) ? a : 0.2f * a;
        m = fmaxf(m, a);
    }
    for (int off = 32; off; off >>= 1) m = fmaxf(m, __shfl_xor(m, off));
    float ss = 0.f, acc0 = 0.f, acc1 = 0.f;
    for (int base = beg; base < end; base += 64) {
        int nch = min(64, end - base);
        int sv = 0;
        float ev = 0.f;
        if (lane < nch) {
            sv = ssrc[base + lane];
            float a = al_s[sv] + ald;
            a = (a > 0.f) ? a : 0.2f * a;
            ev = __expf(a - m);
        }
        ss += ev;
        s_sv[wiw][lane] = sv;
        s_ev[wiw][lane] = ev;
        for (int j0 = 0; j0 < nch; j0 += PF) {
            int np = min(PF, nch - j0);
            float2 hv[PF];
#pragma unroll
            for (int jj = 0; jj < PF; ++jj) {
                if (jj < np) {
                    int svj = s_sv[wiw][j0 + jj];
                    hv[jj] = *(const float2*)(h + (size_t)svj * H + lane * 2);
                }
            }
#pragma unroll
            for (int jj = 0; jj < PF; ++jj) {
                if (jj < np) {
                    float evj = s_ev[wiw][j0 + jj];
                    acc0 += evj * hv[jj].x;
                    acc1 += evj * hv[jj].y;
                }
            }
        }
    }
    for (int off = 32; off; off >>= 1) ss += __shfl_xor(ss, off);
    float inv = 1.f / (ss + 1e-16f);
    ((float2*)(out + (size_t)w * H))[lane] = make_float2(acc0 * inv, acc1 * inv);
}

// ---------------- BN stats ----------------
__global__ void bn_stats(const float* __restrict__ y, float* __restrict__ accum, int N) {
    int f = threadIdx.x & 127;
    int half = threadIdx.x >> 7;
    float sum = 0.f, sumsq = 0.f;
    for (int n = blockIdx.x * 2 + half; n < N; n += gridDim.x * 2) {
        float v = y[(size_t)n * H + f];
        sum += v;
        sumsq += v * v;
    }
    __shared__ float ls[2][128], ls2[2][128];
    ls[half][f] = sum;
    ls2[half][f] = sumsq;
    __syncthreads();
    if (half == 0) {
        atomicAdd(accum + f, ls[0][f] + ls[1][f]);
        atomicAdd(accum + 128 + f, ls2[0][f] + ls2[1][f]);
    }
}

// ---------------- BN apply + relu + residual ----------------
__global__ void bn_apply(float* __restrict__ y, const float* __restrict__ accum,
                         const float* __restrict__ g, const float* __restrict__ be,
                         const float* __restrict__ res, int N) {
    int i = blockIdx.x * blockDim.x + threadIdx.x;
    if (i >= N * H) return;
    int f = i & 127;
    float Ninv = 1.f / (float)N;
    float mu = accum[f] * Ninv;
    float var = accum[128 + f] * Ninv - mu * mu;
    float v = (y[i] - mu) * rsqrtf(var + 1e-5f) * g[f] + be[f];
    y[i] = fmaxf(v, 0.f) + res[i];
}

// ---------------- final fc2: LDS-staged rows ----------------
__global__ void fc2_kernel(const float* __restrict__ in, const float* __restrict__ w,
                           const float* __restrict__ b, float* __restrict__ out,
                           int N, int OUT) {
    __shared__ float wsm[16 * 132];
    __shared__ float xs[16][129];
    int tid = threadIdx.x;
    for (int i = tid; i < OUT * H; i += 256) {
        int o = i >> 7, k = i & 127;
        wsm[o * 132 + k] = w[i];
    }
    int nb = blockIdx.x * 16;
    for (int i = tid; i < 16 * 128; i += 256) {
        int n = i >> 7, k = i & 127;
        int gn = nb + n;
        xs[n][k] = (gn < N) ? in[(size_t)gn * H + k] : 0.f;
    }
    __syncthreads();
    int o = tid & 15;
    int nn = tid >> 4;
    int n = nb + nn;
    if (n >= N || o >= OUT) return;
    const float* xr = xs[nn];
    const float* wr = wsm + o * 132;
    float acc = b[o];
#pragma unroll 8
    for (int k = 0; k < H; k += 4) {
        acc += xr[k] * wr[k] + xr[k + 1] * wr[k + 1] + xr[k + 2] * wr[k + 2] + xr[k + 3] * wr[k + 3];
    }
    out[(size_t)n * OUT + o] = acc;
}

// ---------------- launch ----------------

extern "C" void kernel_launch(void* const* d_in, const int* in_sizes, int n_in,
                              void* d_out, int out_size, void* d_ws, size_t ws_size,
                              hipStream_t stream) {
    const float* x       = (const float*)d_in[0];
    const int*   ei      = (const int*)d_in[1];
    const float* sat_w   = (const float*)d_in[2];
    const float* sat_b   = (const float*)d_in[3];
    const float* neigh_w = (const float*)d_in[4];
    const float* neigh_b = (const float*)d_in[5];
    const float* fus_w   = (const float*)d_in[6];
    const float* fus_b   = (const float*)d_in[7];
    const float* w1      = (const float*)d_in[8];
    const float* as1     = (const float*)d_in[9];
    const float* ad1     = (const float*)d_in[10];
    const float* g1      = (const float*)d_in[12];
    const float* be1     = (const float*)d_in[13];
    const float* w2      = (const float*)d_in[14];
    const float* as2     = (const float*)d_in[15];
    const float* ad2     = (const float*)d_in[16];
    const float* g2      = (const float*)d_in[18];
    const float* be2     = (const float*)d_in[19];
    const float* fc1_w   = (const float*)d_in[20];
    const float* fc1_b   = (const float*)d_in[21];
    const float* fc2_w   = (const float*)d_in[22];
    const float* fc2_b   = (const float*)d_in[23];

    int N = in_sizes[0] / 64;
    int E = in_sizes[1] / 2;
    int Etot = E + N;
    int OUT = in_sizes[23];
    int NB = (N + SCB - 1) / SCB;

    float* ws    = (float*)d_ws;
    float* h0    = ws;                      // N*H
    float* hA    = h0 + (size_t)N * H;      // N*H
    float* agg   = hA + (size_t)N * H;      // N*H
    float* al_s  = agg + (size_t)N * H;     // N
    float* al_d  = al_s + N;                // N
    float* accum = al_d + N;                // 256
    int* rowptr  = (int*)(accum + 256);     // N+1
    int* cnt8    = rowptr + (N + 1);        // 8N (becomes cursor8)
    int* nodeoff = cnt8 + (size_t)8 * N;    // N
    int* blocksum= nodeoff + N;             // NB
    int* blockoff= blocksum + NB;           // NB
    int* ssrc    = blockoff + NB;           // Etot

    const int* srcp = ei;
    const int* dstp = ei + E;

    dim3 b256(256);
    int gEdge = (Etot + 255) / 256;
    int gGemm = (N + 63) / 64;
    int gNH = (N * H + 255) / 256;
    int gWaveN = (N + 3) / 4;

    // ---- fuse ----
    fuse_kernel<<<2048, b256, 0, stream>>>(x, sat_w, sat_b, neigh_w, neigh_b, fus_w, fus_b, h0, N);

    // ---- CSR build (shared by both layers) ----
    fill_u32<<<(8 * N + 255) / 256, b256, 0, stream>>>((unsigned*)cnt8, 0u, 8 * N);
    hist_kernel<<<gEdge, b256, 0, stream>>>(dstp, cnt8, E, Etot, N);
    scan_a<<<NB, SCB, 0, stream>>>(cnt8, nodeoff, blocksum, N);
    scan_b<<<1, 1024, 0, stream>>>(blocksum, blockoff, rowptr + N, NB);
    scan_c<<<NB, SCB, 0, stream>>>(cnt8, nodeoff, blockoff, rowptr, N);
    scatter_kernel<<<gEdge, b256, 0, stream>>>(srcp, dstp, cnt8, ssrc, E, Etot, N);

    // ================= GAT layer 1 =================
    gemm128<<<gGemm, b256, 0, stream>>>(h0, w1, nullptr, 0, hA, N);
    attn_logits<<<gWaveN, b256, 0, stream>>>(hA, as1, ad1, al_s, al_d, N);
    fill_u32<<<1, 256, 0, stream>>>((unsigned*)accum, 0u, 256);
    gat_agg<<<gWaveN, b256, 0, stream>>>(rowptr, ssrc, al_s, al_d, hA, agg, N);
    bn_stats<<<512, b256, 0, stream>>>(agg, accum, N);
    bn_apply<<<gNH, b256, 0, stream>>>(agg, accum, g1, be1, h0, N);

    // ================= GAT layer 2 =================
    gemm128<<<gGemm, b256, 0, stream>>>(agg, w2, nullptr, 0, hA, N);
    attn_logits<<<gWaveN, b256, 0, stream>>>(hA, as2, ad2, al_s, al_d, N);
    fill_u32<<<1, 256, 0, stream>>>((unsigned*)accum, 0u, 256);
    gat_agg<<<gWaveN, b256, 0, stream>>>(rowptr, ssrc, al_s, al_d, hA, h0, N);
    bn_stats<<<512, b256, 0, stream>>>(h0, accum, N);
    bn_apply<<<gNH, b256, 0, stream>>>(h0, accum, g2, be2, agg, N);

    // ================= head =================
    gemm128<<<gGemm, b256, 0, stream>>>(h0, fc1_w, fc1_b, 1, hA, N);
    fc2_kernel<<<(N + 15) / 16, b256, 0, stream>>>(hA, fc2_w, fc2_b, (float*)d_out, N, OUT);
}